// Round 5
// baseline (24119.992 us; speedup 1.0000x reference)
//
#include <hip/hip_runtime.h>
#include <stdint.h>

#define B_ 32
#define T_ 512
#define E_ 256
#define U_ 512
#define N3U_ 1536

typedef __bf16 bf16_t;
typedef bf16_t bf16x8 __attribute__((ext_vector_type(8)));
typedef float f32x4 __attribute__((ext_vector_type(4)));

__device__ __forceinline__ unsigned short f2bf(float x) {
    union { float f; unsigned int u; } v; v.f = x;
    return (unsigned short)((v.u + 0x7fffu + ((v.u >> 16) & 1u)) >> 16);
}

// ---------- Kernel 1: xp = f32( bf16(emb[tokens]) @ bf16(W) + b_in ), one direction ----------
// Inputs are f32 storage (proven R1==R2==R4 + R3-NaN + threshold arithmetic).
// grid (24, 256), block 256. 64x64 tile, K=256 in two 128-halves. f32 out to ws.
__global__ __launch_bounds__(256) void gemm_xproj(
    const int* __restrict__ tokens, const float* __restrict__ emb,
    const float* __restrict__ W, const float* __restrict__ bin,
    float* __restrict__ xp)
{
    const int n0 = blockIdx.x << 6;
    const int m0 = blockIdx.y << 6;
    const int tid  = threadIdx.x;
    const int lane = tid & 63;
    const int w    = tid >> 6;

    __shared__ __align__(16) unsigned short Ash[64][136];
    __shared__ __align__(16) unsigned short Bsh[64][136];

    f32x4 acc[4];
    for (int f = 0; f < 4; ++f) acc[f] = (f32x4){0.f, 0.f, 0.f, 0.f};

    for (int kt = 0; kt < 2; ++kt) {
        const int kbase = kt << 7;
        // stage A: 64 gathered embedding rows x 128 k, f32 -> bf16
        for (int p = 0; p < 8; ++p) {
            int row = (p << 3) + (tid >> 5);
            int c   = tid & 31;
            int tok = tokens[m0 + row];
            float4 v = *(const float4*)&emb[tok * E_ + kbase + (c << 2)];
            ushort4 o;
            o.x = f2bf(v.x); o.y = f2bf(v.y); o.z = f2bf(v.z); o.w = f2bf(v.w);
            *(ushort4*)&Ash[row][c << 2] = o;
        }
        // stage B transposed: Bsh[n][k] = bf16( W[(kbase+k)*N3U + n0+n] )
        for (int p = 0; p < 8; ++p) {
            int kl = (p << 4) + (tid >> 4);
            int j4 = (tid & 15) << 2;
            float4 v = *(const float4*)&W[(kbase + kl) * N3U_ + n0 + j4];
            Bsh[j4 + 0][kl] = f2bf(v.x);
            Bsh[j4 + 1][kl] = f2bf(v.y);
            Bsh[j4 + 2][kl] = f2bf(v.z);
            Bsh[j4 + 3][kl] = f2bf(v.w);
        }
        __syncthreads();
        for (int ks = 0; ks < 4; ++ks) {
            int off = (ks << 5) + ((lane >> 4) << 3);
            bf16x8 a = *(const bf16x8*)&Ash[(w << 4) + (lane & 15)][off];
            for (int f = 0; f < 4; ++f) {
                bf16x8 b = *(const bf16x8*)&Bsh[(f << 4) + (lane & 15)][off];
                acc[f] = __builtin_amdgcn_mfma_f32_16x16x32_bf16(a, b, acc[f], 0, 0, 0);
            }
        }
        __syncthreads();
    }
    // C/D layout: col(N)=lane&15, row(M)=(lane>>4)*4+reg  [verified m89/m91]
    const int col_l = lane & 15;
    const int mrow  = (w << 4) + ((lane >> 4) << 2);
    for (int f = 0; f < 4; ++f) {
        int col = n0 + (f << 4) + col_l;
        float bb = bin[col];
        for (int r = 0; r < 4; ++r) {
            int m = m0 + mrow + r;
            xp[m * N3U_ + col] = acc[f][r] + bb;
        }
    }
}

// ---------- Kernel 2: dead-simple f32 GRU scan, one direction ----------
// grid = 32 blocks (one per batch row), 512 threads (one per hidden unit).
// h lives entirely in this block's LDS; zero cross-block communication.
__global__ __launch_bounds__(512) void gru_scan_simple(
    const float* __restrict__ xp, const float* __restrict__ U,
    const float* __restrict__ br, const int* __restrict__ tokens,
    float* __restrict__ out, int dir)
{
    const int b = blockIdx.x;
    const int u = threadIdx.x;

    __shared__ float hsh[U_];
    hsh[u] = 0.f;
    __syncthreads();

    const float brz = br[u], brr = br[512 + u], brh = br[1024 + u];
    const float* Uz = U + u;

    float hprev = 0.f;   // thread u owns h[u]

    for (int s = 0; s < T_; ++s) {
        const int t = dir ? (T_ - 1 - s) : s;

        const int xrow = (b * T_ + t) * N3U_;
        const float xz = xp[xrow + u];
        const float xr = xp[xrow + 512 + u];
        const float xh = xp[xrow + 1024 + u];
        const int  tok = tokens[b * T_ + t];

        float rz = brz, rr = brr, rh = brh;
        #pragma unroll 8
        for (int k = 0; k < U_; ++k) {
            const float hk = hsh[k];                 // LDS broadcast
            const int   ko = k * N3U_;
            rz = fmaf(hk, Uz[ko], rz);
            rr = fmaf(hk, Uz[ko + 512], rr);
            rh = fmaf(hk, Uz[ko + 1024], rh);
        }

        const float z    = 1.f / (1.f + expf(-(xz + rz)));
        const float rg   = 1.f / (1.f + expf(-(xr + rr)));
        const float cand = tanhf(xh + rg * rh);
        const float hn   = z * hprev + (1.f - z) * cand;
        const float ho   = (tok != 0) ? hn : hprev;   // Keras masking: carry state

        out[(b * T_ + t) * 1024 + dir * 512 + u] = ho;   // f32 output

        __syncthreads();          // everyone done reading hsh for this step
        hsh[u] = ho;
        hprev  = ho;
        __syncthreads();          // h updated before next step's reads
    }
}

extern "C" void kernel_launch(void* const* d_in, const int* in_sizes, int n_in,
                              void* d_out, int out_size, void* d_ws, size_t ws_size,
                              hipStream_t stream)
{
    const size_t XP_BYTES = (size_t)B_ * T_ * N3U_ * 4;   // 100,663,296 (f32, one dir)
    if (ws_size < XP_BYTES) return;  // fail visibly, no OOB writes

    const int*   tokens = (const int*)d_in[0];
    const float* emb    = (const float*)d_in[1];
    const float* W_fw   = (const float*)d_in[2];
    const float* U_fw   = (const float*)d_in[3];
    const float* bin_fw = (const float*)d_in[4];
    const float* brc_fw = (const float*)d_in[5];
    const float* W_bw   = (const float*)d_in[6];
    const float* U_bw   = (const float*)d_in[7];
    const float* bin_bw = (const float*)d_in[8];
    const float* brc_bw = (const float*)d_in[9];

    float* xp   = (float*)d_ws;
    float* outp = (float*)d_out;

    // forward phase
    gemm_xproj<<<dim3(24, 256), dim3(256), 0, stream>>>(tokens, emb, W_fw, bin_fw, xp);
    gru_scan_simple<<<dim3(32), dim3(512), 0, stream>>>(xp, U_fw, brc_fw, tokens, outp, 0);
    // backward phase (reuses xp buffer)
    gemm_xproj<<<dim3(24, 256), dim3(256), 0, stream>>>(tokens, emb, W_bw, bin_bw, xp);
    gru_scan_simple<<<dim3(32), dim3(512), 0, stream>>>(xp, U_bw, brc_bw, tokens, outp, 1);
}

// Round 6
// 13245.044 us; speedup vs baseline: 1.8211x; 1.8211x over previous
//
#include <hip/hip_runtime.h>
#include <stdint.h>

#define B_ 32
#define T_ 512
#define E_ 256
#define U_ 512
#define N3U_ 1536

typedef __bf16 bf16_t;
typedef bf16_t bf16x8 __attribute__((ext_vector_type(8)));
typedef float f32x4 __attribute__((ext_vector_type(4)));

__device__ __forceinline__ unsigned short f2bf(float x) {
    union { float f; unsigned int u; } v; v.f = x;
    return (unsigned short)((v.u + 0x7fffu + ((v.u >> 16) & 1u)) >> 16);
}
__device__ __forceinline__ float bf2f(unsigned short h) {
    union { unsigned int u; float f; } v; v.u = ((unsigned int)h) << 16;
    return v.f;
}

// ---------- Kernel 1: xp[dir] = bf16( bf16(emb[tokens]) @ bf16(W) + b_in ) ----------
// grid (24, 256, 2), block 256. 64x64 tile, K=256 in two 128-halves. bf16 out to ws.
// (GEMM structure correctness proven end-to-end by R5 PASS.)
__global__ __launch_bounds__(256) void gemm_xproj(
    const int* __restrict__ tokens, const float* __restrict__ emb,
    const float* __restrict__ Wf, const float* __restrict__ Wb,
    const float* __restrict__ binf, const float* __restrict__ binb,
    unsigned short* __restrict__ xpf, unsigned short* __restrict__ xpb)
{
    const int dir = blockIdx.z;
    const float* W   = dir ? Wb   : Wf;
    const float* bin = dir ? binb : binf;
    unsigned short* xp = dir ? xpb : xpf;

    const int n0 = blockIdx.x << 6;
    const int m0 = blockIdx.y << 6;
    const int tid  = threadIdx.x;
    const int lane = tid & 63;
    const int w    = tid >> 6;

    __shared__ __align__(16) unsigned short Ash[64][136];
    __shared__ __align__(16) unsigned short Bsh[64][136];

    f32x4 acc[4];
    for (int f = 0; f < 4; ++f) acc[f] = (f32x4){0.f, 0.f, 0.f, 0.f};

    for (int kt = 0; kt < 2; ++kt) {
        const int kbase = kt << 7;
        for (int p = 0; p < 8; ++p) {
            int row = (p << 3) + (tid >> 5);
            int c   = tid & 31;
            int tok = tokens[m0 + row];
            float4 v = *(const float4*)&emb[tok * E_ + kbase + (c << 2)];
            ushort4 o;
            o.x = f2bf(v.x); o.y = f2bf(v.y); o.z = f2bf(v.z); o.w = f2bf(v.w);
            *(ushort4*)&Ash[row][c << 2] = o;
        }
        for (int p = 0; p < 8; ++p) {
            int kl = (p << 4) + (tid >> 4);
            int j4 = (tid & 15) << 2;
            float4 v = *(const float4*)&W[(kbase + kl) * N3U_ + n0 + j4];
            Bsh[j4 + 0][kl] = f2bf(v.x);
            Bsh[j4 + 1][kl] = f2bf(v.y);
            Bsh[j4 + 2][kl] = f2bf(v.z);
            Bsh[j4 + 3][kl] = f2bf(v.w);
        }
        __syncthreads();
        for (int ks = 0; ks < 4; ++ks) {
            int off = (ks << 5) + ((lane >> 4) << 3);
            bf16x8 a = *(const bf16x8*)&Ash[(w << 4) + (lane & 15)][off];
            for (int f = 0; f < 4; ++f) {
                bf16x8 b = *(const bf16x8*)&Bsh[(f << 4) + (lane & 15)][off];
                acc[f] = __builtin_amdgcn_mfma_f32_16x16x32_bf16(a, b, acc[f], 0, 0, 0);
            }
        }
        __syncthreads();
    }
    // C/D layout: col(N)=lane&15, row(M)=(lane>>4)*4+reg
    const int col_l = lane & 15;
    const int mrow  = (w << 4) + ((lane >> 4) << 2);
    for (int f = 0; f < 4; ++f) {
        int col = n0 + (f << 4) + col_l;
        float bb = bin[col];
        for (int r = 0; r < 4; ++r) {
            int m = m0 + mrow + r;
            xp[m * N3U_ + col] = f2bf(acc[f][r] + bb);
        }
    }
}

// ---------- Kernel 2: bidirectional masked GRU scan, weight-stationary MFMA ----------
// 128 blocks: dir(2) x batch-group mg(2) x u-slice us(32).  256 threads (4 waves).
// Block holds its 16-u x 3-gate slice of U as register B-fragments for all 512 steps.
// h in global as bf16 hi+lo, double-buffered; per-(dir,mg) monotonic spin barrier.
// (Machinery validated by R1==R2 bit-identity; only fix vs R1: f32 output.)
__global__ __launch_bounds__(256) void gru_scan(
    const unsigned short* __restrict__ xpf, const unsigned short* __restrict__ xpb,
    const float* __restrict__ Uf, const float* __restrict__ Ub,
    const float* __restrict__ brf, const float* __restrict__ brb,
    const int* __restrict__ tokens,
    unsigned short* __restrict__ hhi, unsigned short* __restrict__ hlo,
    unsigned int* __restrict__ ctr,
    float* __restrict__ out)
{
    const int bx  = blockIdx.x;
    const int us  = bx & 31;
    const int mg  = (bx >> 5) & 1;
    const int dir = bx >> 6;
    const int u0  = us << 4;
    const int tid  = threadIdx.x;
    const int lane = tid & 63;
    const int w    = tid >> 6;
    const int group = (dir << 1) | mg;

    const unsigned short* xp = dir ? xpb : xpf;
    const float* Uw = dir ? Ub : Uf;
    const float* br = dir ? brb : brf;

    __shared__ __align__(16) unsigned short Ahi[16][520];
    __shared__ __align__(16) unsigned short Alo[16][520];
    __shared__ __align__(16) float red[3072];   // [3 gates][4 waves][16 b][16 u]

    // stationary weight fragments: wave w covers k in [w*128, w*128+128)
    bf16x8 wfrag[4][3];
    {
        const int quad = lane >> 4, nl = lane & 15;
        for (int ks = 0; ks < 4; ++ks)
            for (int g = 0; g < 3; ++g) {
                union { bf16x8 v; unsigned short s[8]; } uu;
                for (int j = 0; j < 8; ++j) {
                    int k   = (w << 7) + (ks << 5) + (quad << 3) + j;
                    int col = (g << 9) + u0 + nl;
                    uu.s[j] = f2bf(Uw[k * N3U_ + col]);
                }
                wfrag[ks][g] = uu.v;
            }
    }

    const int bl = tid >> 4;           // local batch row 0..15
    const int ul = tid & 15;           // local u 0..15
    const int bg = (mg << 4) + bl;     // global batch
    const int ug = u0 + ul;            // global u
    float hreg = 0.f;
    const float brz = br[ug], brr = br[512 + ug], brh = br[1024 + ug];

    for (int s = 0; s < T_; ++s) {
        const int t    = dir ? (T_ - 1 - s) : s;
        const int bufr = s & 1, bufw = bufr ^ 1;

        // early independent loads (used in epilogue)
        const int xrow = (bg * T_ + t) * N3U_;
        const unsigned short xzu = xp[xrow + ug];
        const unsigned short xru = xp[xrow + 512 + ug];
        const unsigned short xhu = xp[xrow + 1024 + ug];
        const int tok = tokens[bg * T_ + t];

        // stage this mg's 16 rows of h into LDS, hi+lo
        const int hbase = (((bufr << 1) + dir) << 14) + (mg << 13);
        for (int q = 0; q < 4; ++q) {
            int i = tid + (q << 8);
            int r = i >> 6, c = i & 63;
            uint4 vhi = *(const uint4*)&hhi[hbase + (r << 9) + (c << 3)];
            uint4 vlo = *(const uint4*)&hlo[hbase + (r << 9) + (c << 3)];
            *(uint4*)&Ahi[r][c << 3] = vhi;
            *(uint4*)&Alo[r][c << 3] = vlo;
        }
        __syncthreads();

        f32x4 acc[3];
        acc[0] = (f32x4){0.f,0.f,0.f,0.f};
        acc[1] = (f32x4){0.f,0.f,0.f,0.f};
        acc[2] = (f32x4){0.f,0.f,0.f,0.f};
        for (int ks = 0; ks < 4; ++ks) {
            int off = (w << 7) + (ks << 5) + ((lane >> 4) << 3);
            bf16x8 ahi = *(const bf16x8*)&Ahi[lane & 15][off];
            bf16x8 alo = *(const bf16x8*)&Alo[lane & 15][off];
            for (int g = 0; g < 3; ++g) {
                acc[g] = __builtin_amdgcn_mfma_f32_16x16x32_bf16(ahi, wfrag[ks][g], acc[g], 0, 0, 0);
                acc[g] = __builtin_amdgcn_mfma_f32_16x16x32_bf16(alo, wfrag[ks][g], acc[g], 0, 0, 0);
            }
        }
        // cross-wave (k-split) reduction via LDS
        for (int g = 0; g < 3; ++g)
            for (int r = 0; r < 4; ++r)
                red[(((g << 2) + w) << 8) + ((((lane >> 4) << 2) + r) << 4) + (lane & 15)] = acc[g][r];
        __syncthreads();

        float rz = brz, rr = brr, rh = brh;
        for (int ww = 0; ww < 4; ++ww) {
            rz += red[((0 + ww) << 8) + (bl << 4) + ul];
            rr += red[((4 + ww) << 8) + (bl << 4) + ul];
            rh += red[((8 + ww) << 8) + (bl << 4) + ul];
        }
        float xz = bf2f(xzu), xr = bf2f(xru), xh = bf2f(xhu);
        float z    = 1.f / (1.f + expf(-(xz + rz)));
        float rg   = 1.f / (1.f + expf(-(xr + rr)));
        float cand = tanhf(xh + rg * rh);
        float hn   = z * hreg + (1.f - z) * cand;
        float ho   = (tok != 0) ? hn : hreg;   // Keras masking: carry state
        hreg = ho;

        out[(bg * T_ + t) * 1024 + (dir << 9) + ug] = ho;   // f32 output (the R1 bug fix)

        unsigned short hi = f2bf(ho);
        int hw = (((bufw << 1) + dir) << 14) + (bg << 9) + ug;
        hhi[hw] = hi;
        hlo[hw] = f2bf(ho - bf2f(hi));

        // per-(dir,mg) barrier: monotonic counter, 32 blocks/group
        __threadfence();
        __syncthreads();
        if (tid == 0) {
            atomicAdd(&ctr[group], 1u);
            const unsigned int target = (unsigned int)(s + 1) << 5;
            while (__hip_atomic_load(&ctr[group], __ATOMIC_RELAXED, __HIP_MEMORY_SCOPE_AGENT) < target)
                __builtin_amdgcn_s_sleep(8);
        }
        __syncthreads();
        __threadfence();
    }
}

extern "C" void kernel_launch(void* const* d_in, const int* in_sizes, int n_in,
                              void* d_out, int out_size, void* d_ws, size_t ws_size,
                              hipStream_t stream)
{
    const size_t XP_BYTES = (size_t)B_ * T_ * N3U_ * 2;   // 50,331,648 per dir (bf16)
    const size_t H_OFF    = 2 * XP_BYTES;                 // 100,663,296
    const size_t H_BYTES  = (size_t)2 * 2 * 32 * 512 * 2; // 131,072 (2 bufs x 2 dirs)
    const size_t CTR_OFF  = H_OFF + 2 * H_BYTES;          // 100,925,440
    const size_t NEED     = CTR_OFF + 64;
    if (ws_size < NEED) return;  // fail visibly (R1 proved ws >= NEED)

    const int*   tokens = (const int*)d_in[0];
    const float* emb    = (const float*)d_in[1];
    const float* W_fw   = (const float*)d_in[2];
    const float* U_fw   = (const float*)d_in[3];
    const float* bin_fw = (const float*)d_in[4];
    const float* brc_fw = (const float*)d_in[5];
    const float* W_bw   = (const float*)d_in[6];
    const float* U_bw   = (const float*)d_in[7];
    const float* bin_bw = (const float*)d_in[8];
    const float* brc_bw = (const float*)d_in[9];

    char* ws = (char*)d_ws;
    unsigned short* xpf = (unsigned short*)ws;
    unsigned short* xpb = (unsigned short*)(ws + XP_BYTES);
    unsigned short* hhi = (unsigned short*)(ws + H_OFF);
    unsigned short* hlo = (unsigned short*)(ws + H_OFF + H_BYTES);
    unsigned int*   ctr = (unsigned int*)(ws + CTR_OFF);
    float* outp = (float*)d_out;

    // zero h state (both buffers) + barrier counters, every call
    hipMemsetAsync(ws + H_OFF, 0, 2 * H_BYTES + 64, stream);

    gemm_xproj<<<dim3(24, 256, 2), dim3(256), 0, stream>>>(
        tokens, emb, W_fw, W_bw, bin_fw, bin_bw, xpf, xpb);

    void* args[] = { (void*)&xpf, (void*)&xpb, (void*)&U_fw, (void*)&U_bw,
                     (void*)&brc_fw, (void*)&brc_bw, (void*)&tokens,
                     (void*)&hhi, (void*)&hlo, (void*)&ctr, (void*)&outp };
    hipLaunchCooperativeKernel((const void*)gru_scan, dim3(128), dim3(256), args, 0, stream);
}